// Round 7
// baseline (298.988 us; speedup 1.0000x reference)
//
#include <hip/hip_runtime.h>
#include <stdint.h>

// WeightsDropout: per row of 4096 f32 (uniform in (1e-4,1)), drop the 2048
// smallest (stable tie-break: smaller index dropped first), softmax survivors.
//
// R10: WAVE-PER-ROW, STREAMING, ZERO BARRIERS. Evidence: R4/R6/R8 all show
// per-row latency ~18-21us (time / resident-row-batches) invariant across
// barrier count (6-8), occupancy (48-76%), and spills (present/absent) ->
// throughput is resident_rows/row_latency; cross-wave phase rendezvous is the
// floor. R10 removes ALL cross-wave coordination: one wave owns one row,
// wave-private LDS (hist 1KB + pool 4KB + cand), sync = wave-internal fences
// only. Pass1 machinery minimized vs R8 (VALU 55%): band elems appended by
// individual LDS atomics (~6 ops/elem) instead of per-element
// ballot+leader+popc (~30 ops/elem). Survivor exp-sum analytic:
// sumHigh (>=P2, pass1) + sumAbove (pool sweep, buckets>selb) + in-bucket
// candidates -> no separate sum pass. Pass2 re-reads row (L3) + NT store.
// 7 blocks/CU (22KB LDS) = 28 independent waves/CU; VGPR ~45, no arrays.
// Exact wave-level streaming-bisection fallback (never taken for uniform).
constexpr int N     = 4096;
constexpr int KSEL  = 2048;          // int(N * 0.5)
constexpr int BLOCK = 256;
constexpr int WPB   = 4;             // waves (=rows) per block
constexpr int VPL   = 16;            // uint4 loads per lane (64 elems)
constexpr int NB    = 256;           // fine buckets over the band
constexpr int POOL  = 512;           // band pool (E=410, sd=19 -> 5.3 sigma)
constexpr int CAP   = 48;            // crossing-bucket candidates (E=1.6)
constexpr float P1  = 0.45f;
constexpr float P2  = 0.55f;
constexpr float BSCALE = 2560.0f;    // NB / (P2 - P1)

typedef float vfloat4 __attribute__((ext_vector_type(4)));

__global__ __launch_bounds__(BLOCK, 6)
void wdrop_kernel(const float* __restrict__ w, float* __restrict__ out) {
    const int wid = threadIdx.x >> 6, lane = threadIdx.x & 63;
    const uint64_t row = (uint64_t)blockIdx.x * WPB + wid;
    const uint4* wf = (const uint4*)(w + row * N);

    __shared__ alignas(16) int hist[WPB][NB];   // wave-private
    __shared__ uint2    pool[WPB][POOL];
    __shared__ uint32_t candB[WPB][CAP];
    __shared__ int      candI[WPB][CAP];
    __shared__ int      pcnt[WPB], ccnt[WPB];

    // ---- zero own hist/counters (wave-internal ordering only)
    ((int4*)hist[wid])[lane] = int4{0, 0, 0, 0};
    if (lane == 0) { pcnt[wid] = 0; ccnt[wid] = 0; }
    __threadfence_block();

    // ---- pass 1: stream row; clo, sumHigh, band -> hist + pool (per-lane
    //      atomics, no ballot machinery)
    int clo = 0;
    float sumHigh = 0.0f;
    const int lane4 = lane * 4;
#pragma unroll
    for (int j = 0; j < VPL; ++j) {
        const uint4 u = wf[j * 64 + lane];
        const uint32_t bits[4] = {u.x, u.y, u.z, u.w};
#pragma unroll
        for (int c = 0; c < 4; ++c) {
            const float f = __uint_as_float(bits[c]);
            if (f < P1) {
                ++clo;
            } else if (f >= P2) {
                sumHigh += __expf(f);
            } else {
                const int bk = min((int)((f - P1) * BSCALE), NB - 1);
                atomicAdd(&hist[wid][bk], 1);
                const int slot = atomicAdd(&pcnt[wid], 1);
                if (slot < POOL)
                    pool[wid][slot] =
                        make_uint2(bits[c], (uint32_t)(j * 256 + lane4 + c));
            }
        }
    }
#pragma unroll
    for (int off = 32; off > 0; off >>= 1) {
        clo += __shfl_xor(clo, off, 64);
        sumHigh += __shfl_xor(sumHigh, off, 64);
    }
    __threadfence_block();

    // ---- scan own hist (int4/lane + shuffle scan) -> crossing bucket
    const int4 hh = ((const int4*)hist[wid])[lane];
    const int a0 = hh.x, a1 = a0 + hh.y, a2 = a1 + hh.z, a3 = a2 + hh.w;
    int sc = a3;
#pragma unroll
    for (int off = 1; off < 64; off <<= 1) {
        const int u = __shfl_up(sc, off, 64);
        if (lane >= off) sc += u;
    }
    const int base = sc - a3;                 // exclusive prefix of lane's 4
    const int tot  = __shfl(sc, 63, 64);      // band total (uniform)
    const int pn   = pcnt[wid];               // uniform LDS read

    bool ok = (clo < KSEL) && (clo + tot >= KSEL) && (pn <= POOL);
    int selb = -1, jms = 0;
    if (ok) {
        const int jrank = KSEL - clo;         // 1-indexed rank within band
        const int inc[4] = {base + a0, base + a1, base + a2, base + a3};
        const int exc[4] = {base, base + a0, base + a1, base + a2};
#pragma unroll
        for (int i = 0; i < 4; ++i)
            if (exc[i] < jrank && jrank <= inc[i]) {
                selb = lane * 4 + i;
                jms  = jrank - exc[i] - 1;    // 0-indexed rank in bucket
            }
        const unsigned long long bb = __ballot(selb >= 0);
        const int src = __ffsll(bb) - 1;
        selb = __shfl(selb, src, 64);
        jms  = __shfl(jms,  src, 64);
    }

    // ---- pool sweep: sumAbove (buckets > selb) + candidates (bucket == selb)
    uint32_t T = 0; int ti = 0; float inv = 0.0f;
    if (ok) {
        float sumAbove = 0.0f;
        for (int k = 0; k < pn; k += 64) {
            const int id = k + lane;
            if (id < pn) {
                const uint2 pe = pool[wid][id];
                const float pf = __uint_as_float(pe.x);
                const int bk = min((int)((pf - P1) * BSCALE), NB - 1);
                if (bk > selb) {
                    sumAbove += __expf(pf);
                } else if (bk == selb) {
                    const int s = atomicAdd(&ccnt[wid], 1);
                    if (s < CAP) { candB[wid][s] = pe.x; candI[wid][s] = (int)pe.y; }
                }
            }
        }
#pragma unroll
        for (int off = 32; off > 0; off >>= 1)
            sumAbove += __shfl_xor(sumAbove, off, 64);
        __threadfence_block();
        const int cn = ccnt[wid];             // uniform
        if (cn > CAP) ok = false;
        if (ok) {
            // exact lex rank among candidates -> k-th smallest (bits, idx)
            bool found = false; uint32_t mT = 0; int mI = 0;
            if (lane < cn) {
                const uint32_t myb = candB[wid][lane];
                const int      myi = candI[wid][lane];
                int rank = 0;
                for (int q = 0; q < cn; ++q)
                    rank += (candB[wid][q] < myb) ||
                            (candB[wid][q] == myb && candI[wid][q] < myi);
                if (rank == jms) { found = true; mT = myb; mI = myi; }
            }
            const unsigned long long bb = __ballot(found);
            const int src = __ffsll(bb) - 1;
            T  = (uint32_t)__shfl((int)mT, src, 64);
            ti = __shfl(mI, src, 64);
            float sb = 0.0f;                  // in-bucket survivor sum
            if (lane < cn) {
                const uint32_t cbv = candB[wid][lane];
                const int      civ = candI[wid][lane];
                if (cbv > T || (cbv == T && civ > ti))
                    sb = __expf(__uint_as_float(cbv));
            }
#pragma unroll
            for (int off = 32; off > 0; off >>= 1) sb += __shfl_xor(sb, off, 64);
            inv = 1.0f / (sumHigh + sumAbove + sb);
        }
    }

    // ---- exact wave-level streaming fallback (never taken for uniform data)
    if (!ok) {
        uint32_t blo = 0u, bhi = 0x7f7fffffu;
        while (blo < bhi) {
            const uint32_t mid = blo + ((bhi - blo) >> 1);
            int c = 0;
#pragma unroll
            for (int j = 0; j < VPL; ++j) {
                const uint4 u = wf[j * 64 + lane];
                c += (u.x <= mid) + (u.y <= mid) + (u.z <= mid) + (u.w <= mid);
            }
#pragma unroll
            for (int off = 32; off > 0; off >>= 1) c += __shfl_xor(c, off, 64);
            if (c >= KSEL) bhi = mid; else blo = mid + 1;
        }
        T = blo;
        int c = 0;
#pragma unroll
        for (int j = 0; j < VPL; ++j) {
            const uint4 u = wf[j * 64 + lane];
            c += (u.x < T) + (u.y < T) + (u.z < T) + (u.w < T);
        }
#pragma unroll
        for (int off = 32; off > 0; off >>= 1) c += __shfl_xor(c, off, 64);
        const int need = KSEL - c;
        int ilo = 0, ihi = N - 1;
        while (ilo < ihi) {
            const int imid = (ilo + ihi) >> 1;
            int cc = 0;
#pragma unroll
            for (int j = 0; j < VPL; ++j) {
                const uint4 u = wf[j * 64 + lane];
                const int i0 = j * 256 + lane4;
                cc += (u.x == T && i0 + 0 <= imid) + (u.y == T && i0 + 1 <= imid) +
                      (u.z == T && i0 + 2 <= imid) + (u.w == T && i0 + 3 <= imid);
            }
#pragma unroll
            for (int off = 32; off > 0; off >>= 1) cc += __shfl_xor(cc, off, 64);
            if (cc >= need) ihi = imid; else ilo = imid + 1;
        }
        ti = ilo;
        float acc = 0.0f;
#pragma unroll
        for (int j = 0; j < VPL; ++j) {
            const uint4 u = wf[j * 64 + lane];
            const uint32_t bits[4] = {u.x, u.y, u.z, u.w};
            const int i0 = j * 256 + lane4;
#pragma unroll
            for (int c2 = 0; c2 < 4; ++c2) {
                const bool keep = (bits[c2] > T) || (bits[c2] == T && i0 + c2 > ti);
                if (keep) acc += __expf(__uint_as_float(bits[c2]));
            }
        }
#pragma unroll
        for (int off = 32; off > 0; off >>= 1) acc += __shfl_xor(acc, off, 64);
        inv = 1.0f / acc;
    }

    // ---- pass 2: re-read row (L3), keep -> exp*inv, NT store
    vfloat4* of = (vfloat4*)(out + row * N);
#pragma unroll
    for (int j = 0; j < VPL; ++j) {
        const uint4 u = wf[j * 64 + lane];
        const uint32_t bits[4] = {u.x, u.y, u.z, u.w};
        const int i0 = j * 256 + lane4;
        vfloat4 o;
#pragma unroll
        for (int c = 0; c < 4; ++c) {
            const uint32_t b = bits[c];
            const bool keep = (b > T) || (b == T && i0 + c > ti);
            o[c] = keep ? __expf(__uint_as_float(b)) * inv : 0.0f;
        }
        __builtin_nontemporal_store(o, &of[j * 64 + lane]);
    }
}

extern "C" void kernel_launch(void* const* d_in, const int* in_sizes, int n_in,
                              void* d_out, int out_size, void* d_ws, size_t ws_size,
                              hipStream_t stream) {
    const float* w = (const float*)d_in[0];
    float* out = (float*)d_out;
    const int rows = in_sizes[0] / N;            // 8192
    wdrop_kernel<<<rows / WPB, BLOCK, 0, stream>>>(w, out);
}

// Round 8
// 232.061 us; speedup vs baseline: 1.2884x; 1.2884x over previous
//
#include <hip/hip_runtime.h>
#include <stdint.h>

// WeightsDropout: per row of 4096 f32 (uniform in (1e-4,1)), drop the 2048
// smallest (stable tie-break: smaller index dropped first), softmax survivors.
//
// R11: R5b (best measured, ~76-78us kernel) slimmed on BOTH axes:
//  - instruction fat: no max-reduce (inputs<1 -> softmax shift-invariant,
//    proven R6/R8b/R10); candidate-gather FOLDED into pass1 via per-wave
//    pools (2 LDS atomics for the ~1.6 band elems/thread only; no
//    ballot/leader machinery, no separate gather re-scan pass).
//  - phase structure: wave-segmented hist (4x64 coarse buckets) -> each wave
//    zeroes+fills its own segment, no zero-visibility barrier; wave0 merges
//    4 segments in the scan. 3 barriers total (was 6).
//  - fallback bisection runs on the register-resident row (no global
//    re-reads); block-uniform, never taken for uniform data.
// Row stays in 16 VGPRs (R5b layout); __launch_bounds__(256,8) pins the
// 64-VGPR class; LDS 6.6KB -> 8 blocks/CU.
constexpr int N     = 4096;
constexpr int KSEL  = 2048;          // int(N * 0.5)
constexpr int BLOCK = 256;
constexpr int NW    = BLOCK / 64;    // 4 waves
constexpr int EPT   = 16;            // elements per thread
constexpr int NB    = 64;            // coarse buckets over the band
constexpr int PCAP  = 160;           // per-wave pool cap (E=102, sd=9.6, +6sd)
constexpr int CCAP  = 48;            // crossing-bucket candidates (E=6.4)
constexpr float P1  = 0.45f;
constexpr float P2  = 0.55f;
constexpr float BSCALE = 640.0f;     // NB / (P2 - P1)

typedef float vfloat4 __attribute__((ext_vector_type(4)));

__global__ __launch_bounds__(BLOCK, 8)
void wdrop_kernel(const float* __restrict__ w, float* __restrict__ out) {
    const int t = threadIdx.x, wid = t >> 6, lane = t & 63;
    const uint64_t row = blockIdx.x;

    __shared__ int      hist[NW][NB];      // wave-segmented
    __shared__ int      pcnt[NW];
    __shared__ uint2    pool[NW][PCAP];    // wave-private band pools
    __shared__ int      wclo[NW];
    __shared__ int      redi[NW];          // fallback reduce slots
    __shared__ float    redf[NW];
    __shared__ uint32_t candB[CCAP];
    __shared__ int      candI[CCAP];
    __shared__ uint32_t bT, bI;
    __shared__ int      bFlag;

    // ---- load row: 4 x dwordx4 per thread, register-resident
    uint32_t v[EPT];
    {
        const uint4* wf = (const uint4*)(w + row * N);
        uint4 u[4];
#pragma unroll
        for (int j = 0; j < 4; ++j) u[j] = wf[j * BLOCK + t];
#pragma unroll
        for (int j = 0; j < 4; ++j) {
            v[j*4+0] = u[j].x; v[j*4+1] = u[j].y;
            v[j*4+2] = u[j].z; v[j*4+3] = u[j].w;
        }
    }

    // ---- wave-private zero (no cross-wave visibility needed -> no barrier)
    hist[wid][lane] = 0;
    if (lane == 0) pcnt[wid] = 0;
    __threadfence_block();   // order zeroing before this wave's atomics

    // ---- pass 1: clo count + band -> own hist segment + own pool
    int clo = 0;
#pragma unroll
    for (int e = 0; e < EPT; ++e) {
        const float f = __uint_as_float(v[e]);
        if (f < P1) {
            ++clo;
        } else if (f < P2) {
            const int bk = min((int)((f - P1) * BSCALE), NB - 1);
            atomicAdd(&hist[wid][bk], 1);
            const int slot = atomicAdd(&pcnt[wid], 1);
            if (slot < PCAP)
                pool[wid][slot] = make_uint2(
                    v[e], (uint32_t)(((e >> 2) * BLOCK + t) * 4 + (e & 3)));
        }
    }
#pragma unroll
    for (int off = 32; off > 0; off >>= 1) clo += __shfl_xor(clo, off, 64);
    if (lane == 0) wclo[wid] = clo;
    __syncthreads();                                          // B1 (pass1)

    // ---- wave 0: merge-scan 4 hist segments, select bucket, rank candidates
    if (wid == 0) {
        const int cloB = wclo[0] + wclo[1] + wclo[2] + wclo[3];
        const int h = hist[0][lane] + hist[1][lane] + hist[2][lane] + hist[3][lane];
        int sc = h;
#pragma unroll
        for (int off = 1; off < 64; off <<= 1) {
            const int u = __shfl_up(sc, off, 64);
            if (lane >= off) sc += u;
        }
        const int tot = __shfl(sc, 63, 64);
        bool ok = (cloB < KSEL) && (cloB + tot >= KSEL) &&
                  (pcnt[0] <= PCAP) && (pcnt[1] <= PCAP) &&
                  (pcnt[2] <= PCAP) && (pcnt[3] <= PCAP);
        int selb = -1, jms = 0;
        if (ok) {
            const int jrank = KSEL - cloB;        // 1-indexed rank in band
            const int exc = sc - h;
            const bool hit = (exc < jrank) && (jrank <= sc);
            const unsigned long long bb = __ballot(hit);
            const int src = __ffsll(bb) - 1;
            selb = __shfl(lane, src, 64);
            jms  = __shfl(jrank - exc - 1, src, 64);   // 0-indexed in bucket
        }
        int cn = 0;
        if (ok) {
            // sweep the 4 pools, ballot-compact bucket==selb into cand
#pragma unroll
            for (int wv = 0; wv < NW; ++wv) {
                const int pn = pcnt[wv];
                for (int k = 0; k < pn; k += 64) {
                    const int id = k + lane;
                    bool in = false; uint2 pe = make_uint2(0u, 0u);
                    if (id < pn) {
                        pe = pool[wv][id];
                        const float pf = __uint_as_float(pe.x);
                        in = (min((int)((pf - P1) * BSCALE), NB - 1) == selb);
                    }
                    const unsigned long long m = __ballot(in);
                    if (in) {
                        const int slot = cn + __popcll(m & ((1ull << lane) - 1ull));
                        if (slot < CCAP) { candB[slot] = pe.x; candI[slot] = (int)pe.y; }
                    }
                    cn += __popcll(m);
                }
            }
            if (cn > CCAP) ok = false;
        }
        if (ok) {
            __threadfence_block();
            // exact lex rank among candidates -> k-th smallest (bits, idx)
            if (lane < cn) {
                const uint32_t myb = candB[lane]; const int myi = candI[lane];
                int rank = 0;
                for (int q = 0; q < cn; ++q)
                    rank += (candB[q] < myb) || (candB[q] == myb && candI[q] < myi);
                if (rank == jms) { bT = myb; bI = (uint32_t)myi; }
            }
        }
        if (lane == 0) bFlag = ok ? 0 : 1;
    }
    __syncthreads();                                          // B2 (threshold)

    // ---- exact fallback on register-resident data (block-uniform; never
    //      taken for uniform inputs)
    if (bFlag) {
        uint32_t blo = 0u, bhi = 0x7f7fffffu;
        while (blo < bhi) {
            const uint32_t mid = blo + ((bhi - blo) >> 1);
            int c = 0;
#pragma unroll
            for (int e = 0; e < EPT; ++e) c += (v[e] <= mid);
#pragma unroll
            for (int off = 32; off > 0; off >>= 1) c += __shfl_xor(c, off, 64);
            if (lane == 0) redi[wid] = c;
            __syncthreads();
            const int tot = redi[0] + redi[1] + redi[2] + redi[3];
            __syncthreads();
            if (tot >= KSEL) bhi = mid; else blo = mid + 1;
        }
        const uint32_t T = blo;
        int c = 0;
#pragma unroll
        for (int e = 0; e < EPT; ++e) c += (v[e] < T);
#pragma unroll
        for (int off = 32; off > 0; off >>= 1) c += __shfl_xor(c, off, 64);
        if (lane == 0) redi[wid] = c;
        __syncthreads();
        const int clt = redi[0] + redi[1] + redi[2] + redi[3];
        __syncthreads();
        const int need = KSEL - clt;
        int ilo = 0, ihi = N - 1;
        while (ilo < ihi) {
            const int imid = (ilo + ihi) >> 1;
            int cc = 0;
#pragma unroll
            for (int e = 0; e < EPT; ++e) {
                const int idx = ((e >> 2) * BLOCK + t) * 4 + (e & 3);
                cc += (v[e] == T && idx <= imid);
            }
#pragma unroll
            for (int off = 32; off > 0; off >>= 1) cc += __shfl_xor(cc, off, 64);
            if (lane == 0) redi[wid] = cc;
            __syncthreads();
            const int tot = redi[0] + redi[1] + redi[2] + redi[3];
            __syncthreads();
            if (tot >= need) ihi = imid; else ilo = imid + 1;
        }
        if (t == 0) { bT = T; bI = (uint32_t)ilo; }
        __syncthreads();
    }

    // ---- keep + exp (no max) + block sum, then scale + NT store
    const uint32_t T = bT; const int ti = (int)bI;
    float acc = 0.0f;
#pragma unroll
    for (int e = 0; e < EPT; ++e) {
        const int idx = ((e >> 2) * BLOCK + t) * 4 + (e & 3);
        const bool keep = (v[e] > T) || (v[e] == T && idx > ti);
        const float ev = keep ? __expf(__uint_as_float(v[e])) : 0.0f;
        v[e] = __float_as_uint(ev);
        acc += ev;
    }
#pragma unroll
    for (int off = 32; off > 0; off >>= 1) acc += __shfl_xor(acc, off, 64);
    if (lane == 0) redf[wid] = acc;
    __syncthreads();                                          // B3 (sum)
    const float inv = 1.0f / (redf[0] + redf[1] + redf[2] + redf[3]);

    vfloat4* of = (vfloat4*)(out + row * N);
#pragma unroll
    for (int j = 0; j < 4; ++j) {
        vfloat4 o;
        o.x = __uint_as_float(v[j*4+0]) * inv;
        o.y = __uint_as_float(v[j*4+1]) * inv;
        o.z = __uint_as_float(v[j*4+2]) * inv;
        o.w = __uint_as_float(v[j*4+3]) * inv;
        __builtin_nontemporal_store(o, &((vfloat4*)of)[j * BLOCK + t]);
    }
}

extern "C" void kernel_launch(void* const* d_in, const int* in_sizes, int n_in,
                              void* d_out, int out_size, void* d_ws, size_t ws_size,
                              hipStream_t stream) {
    const float* w = (const float*)d_in[0];
    float* out = (float*)d_out;
    const int rows = in_sizes[0] / N;            // 8192
    wdrop_kernel<<<rows, BLOCK, 0, stream>>>(w, out);
}